// Round 7
// baseline (287.759 us; speedup 1.0000x reference)
//
#include <hip/hip_runtime.h>
#include <hip/hip_bf16.h>

// LocEncoder fused, round 7: CSR pipeline.
//
//   h1 = relu(u[src] - w[dst]),  u/w precomputed bf16 (round-5 algebra)
//
//  k0: memset gcnt[98] (1 KB)
//  k1 precompute: wave-per-node VALU -> u16,w16 [N,64] bf16 (coalesced rows)
//  k2 partition: LDS counting-sort per 4096-edge batch -> 98 dst-buckets
//      (packed src<<10|dst_low), coalesced run flushes (round-6, unchanged)
//  k3 csrify: block per bucket (1024 thr): LDS hist over 1024 local nodes,
//      block scan, scatter into block-EXCLUSIVE 64-KB csr region ->
//      nodeStart/nodeDeg + dst-sorted csr. Full-line writebacks only.
//  k4 aggregate: block = 64 nodes, NO LDS, no per-node cap (exact):
//      contiguous csr reads, u16 gathers, GEMM2 MFMA, register max,
//      one coalesced store per node.

#define N_NODES 100000
#define N_EDGES 1600000
#define NBKT 98        // dst >> 10
#define BKT_CAP 18432  // mean 16384 edges/bucket + 16 sigma
#define BATCH 4096     // edges per partition block
#define WPB 4

typedef short short8  __attribute__((ext_vector_type(8)));
typedef float float4v __attribute__((ext_vector_type(4)));

__device__ inline short f2bf(float f) {  // fp32->bf16 RNE
    union { float f; unsigned u; } v; v.f = f;
    unsigned u = v.u;
    u += 0x7fffu + ((u >> 16) & 1u);
    return (short)(u >> 16);
}
__device__ inline short2 f2bf2(float a, float b) {  // v_cvt_pk_bf16_f32
    __hip_bfloat162 h = __float22bfloat162_rn(make_float2(a, b));
    return *(short2*)&h;
}
__device__ inline float bf2f(short s) {
    union { unsigned u; float f; } v;
    v.u = ((unsigned)(unsigned short)s) << 16;
    return v.f;
}

// ---- k1: u/w precompute, wave per node, coalesced 2-B-per-lane row stores ----
__global__ __launch_bounds__(256) void precompute_kernel(
    const float* __restrict__ x,    // [N,13]
    const float* __restrict__ pos,  // [N,3]
    const float* __restrict__ W1,   // [16,64]
    const float* __restrict__ b1,   // [64]
    unsigned short* __restrict__ u16,  // [N,64] bf16: x@W1a + pos@W1b + b1
    unsigned short* __restrict__ w16)  // [N,64] bf16: pos@W1b
{
    const int lane = threadIdx.x & 63;
    float w1c[16];
#pragma unroll
    for (int k = 0; k < 16; ++k) w1c[k] = W1[k * 64 + lane];
    const float b1c = b1[lane];

    const int waveId = blockIdx.x * WPB + (threadIdx.x >> 6);
    const int nwave  = gridDim.x * WPB;

    for (int node = waveId; node < N_NODES; node += nwave) {
        float m = 0.f;
        if (lane < 13) m = x[node * 13 + lane];
        else if (lane < 16) m = pos[node * 3 + (lane - 13)];

        float acc = b1c, accw = 0.f;
#pragma unroll
        for (int k = 0; k < 13; ++k)
            acc = fmaf(__shfl(m, k), w1c[k], acc);
#pragma unroll
        for (int k = 13; k < 16; ++k) {
            const float p = __shfl(m, k);
            acc  = fmaf(p, w1c[k], acc);
            accw = fmaf(p, w1c[k], accw);
        }
        u16[node * 64 + lane] = (unsigned short)f2bf(acc);
        w16[node * 64 + lane] = (unsigned short)f2bf(accw);
    }
}

// ---- k2: dst-radix partition (round-6, unchanged) ----
__global__ __launch_bounds__(256) void partition_kernel(
    const int* __restrict__ ei,        // [2,E]
    int* __restrict__ gcnt,            // [NBKT]
    int* __restrict__ bucketData)      // [NBKT, BKT_CAP] packed (src<<10|dlow)
{
    __shared__ int hist[NBKT], off0[NBKT], offc[NBKT], gbase[NBKT];
    __shared__ int sortedW[BATCH];
    __shared__ unsigned short sortedB[BATCH];

    const int tid  = threadIdx.x;
    const int lane = tid & 63;
    const int wv   = tid >> 6;
    const int e0   = blockIdx.x * BATCH;
    const int nn   = (N_EDGES - e0) < BATCH ? (N_EDGES - e0) : BATCH;

    if (tid < NBKT) hist[tid] = 0;
    __syncthreads();

    for (int i = tid; i < nn; i += 256)
        atomicAdd(&hist[ei[N_EDGES + e0 + i] >> 10], 1);
    __syncthreads();

    if (wv == 0) {  // exclusive scan of hist[0..97]
        int a = (lane < NBKT) ? hist[lane] : 0;
        int b = (64 + lane < NBKT) ? hist[64 + lane] : 0;
        for (int d = 1; d < 64; d <<= 1) { int t = __shfl_up(a, d); if (lane >= d) a += t; }
        for (int d = 1; d < 64; d <<= 1) { int t = __shfl_up(b, d); if (lane >= d) b += t; }
        const int tot = __shfl(a, 63);
        if (lane < NBKT) off0[lane] = a - hist[lane];
        if (64 + lane < NBKT) off0[64 + lane] = tot + b - hist[64 + lane];
    }
    __syncthreads();

    if (tid < NBKT) {
        gbase[tid] = atomicAdd(&gcnt[tid], hist[tid]);
        offc[tid]  = off0[tid];
    }
    __syncthreads();

    for (int i = tid; i < nn; i += 256) {
        const int s = ei[e0 + i];
        const int d = ei[N_EDGES + e0 + i];
        const int b = d >> 10;
        const int p = atomicAdd(&offc[b], 1);
        sortedW[p] = (s << 10) | (d & 1023);
        sortedB[p] = (unsigned short)b;
    }
    __syncthreads();

    for (int i = tid; i < nn; i += 256) {
        const int b  = sortedB[i];
        const int gd = gbase[b] + (i - off0[b]);
        if (gd < BKT_CAP) bucketData[b * BKT_CAP + gd] = sortedW[i];
    }
}

// ---- k3: csrify — per-bucket counting sort into CSR ----
__global__ __launch_bounds__(1024) void csrify_kernel(
    const int* __restrict__ gcnt,        // [NBKT]
    const int* __restrict__ bucketData,  // [NBKT, BKT_CAP]
    int* __restrict__ nodeStart,         // [N]
    int* __restrict__ nodeDeg,           // [N]
    int* __restrict__ csr)               // [NBKT, BKT_CAP] src, dst-sorted
{
    __shared__ int hist[1024];
    __shared__ int wsum[16];

    const int tid  = threadIdx.x;
    const int lane = tid & 63;
    const int wv   = tid >> 6;
    const int bkt  = blockIdx.x;

    hist[tid] = 0;
    __syncthreads();

    int bcnt = gcnt[bkt]; bcnt = bcnt < BKT_CAP ? bcnt : BKT_CAP;
    const int* bd = bucketData + bkt * BKT_CAP;

    for (int i = tid; i < bcnt; i += 1024)
        atomicAdd(&hist[bd[i] & 1023], 1);
    __syncthreads();

    // block exclusive scan over 1024 entries (wave scan + wave-sum scan)
    const int v = hist[tid];
    int incl = v;
    for (int d = 1; d < 64; d <<= 1) { int t = __shfl_up(incl, d); if (lane >= d) incl += t; }
    if (lane == 63) wsum[wv] = incl;
    __syncthreads();
    if (wv == 0 && lane < 16) {
        int s = wsum[lane];
        for (int d = 1; d < 16; d <<= 1) { int t = __shfl_up(s, d); if (lane >= d) s += t; }
        wsum[lane] = s;  // inclusive
    }
    __syncthreads();
    const int excl = incl - v + (wv ? wsum[wv - 1] : 0);

    const int node = bkt * 1024 + tid;
    if (node < N_NODES) {
        nodeStart[node] = bkt * BKT_CAP + excl;
        nodeDeg[node]   = v;
    }
    __syncthreads();
    hist[tid] = excl;  // running scatter offsets
    __syncthreads();

    int* cbase = csr + bkt * BKT_CAP;  // block-exclusive 72-KB region
    for (int i = tid; i < bcnt; i += 1024) {
        const int w  = bd[i];
        const int p  = atomicAdd(&hist[w & 1023], 1);
        cbase[p] = w >> 10;
    }
}

// ---- k4: aggregate — CSR reads, GEMM2 MFMA, no LDS ----
__global__ __launch_bounds__(256, 6) void aggregate_kernel(
    const unsigned short* __restrict__ u16,  // [N,64] bf16
    const unsigned short* __restrict__ w16,  // [N,64] bf16
    const float* __restrict__ W2,            // [64,64]
    const float* __restrict__ b2,            // [64]
    const int*   __restrict__ nodeStart,     // [N]
    const int*   __restrict__ nodeDeg,       // [N]
    const int*   __restrict__ csr,           // src, dst-sorted
    float*       __restrict__ out)           // [N,64]
{
    const int lane = threadIdx.x & 63;
    const int wv   = threadIdx.x >> 6;
    const int q = lane >> 4, n = lane & 15;

    short8 w2f[2][4];  // B[k = s*32 + q*8 + j][n + 16t]
#pragma unroll
    for (int s = 0; s < 2; ++s)
#pragma unroll
        for (int t = 0; t < 4; ++t)
#pragma unroll
            for (int j = 0; j < 8; ++j)
                w2f[s][t][j] = f2bf(W2[(s * 32 + q * 8 + j) * 64 + (n + 16 * t)]);
    float b2c[4];
#pragma unroll
    for (int t = 0; t < 4; ++t) b2c[t] = b2[n + 16 * t];

    const int node0 = blockIdx.x * 64 + wv * 16;

    for (int k = 0; k < 16; ++k) {
        const int node = node0 + k;
        if (node >= N_NODES) break;  // wave-uniform
        const int start = nodeStart[node];
        const int deg   = nodeDeg[node];

        const short8 wlo = *(const short8*)(w16 + node * 64 + q * 8);
        const short8 whi = *(const short8*)(w16 + node * 64 + 32 + q * 8);
        float wf[16];
#pragma unroll
        for (int j = 0; j < 8; ++j) { wf[j] = bf2f(wlo[j]); wf[8 + j] = bf2f(whi[j]); }

        float vmax[4] = {0.f, 0.f, 0.f, 0.f};  // 0-init == relu + empty=0

        for (int base = 0; base < deg; base += 16) {
            const int rows = (deg - base) < 16 ? (deg - base) : 16;
            const int src  = (n < rows) ? csr[start + base + n] : 0;

            const short8 ulo = *(const short8*)(u16 + src * 64 + q * 8);
            const short8 uhi = *(const short8*)(u16 + src * 64 + 32 + q * 8);

            union { short8 v; short2 h[4]; } alo, ahi;
#pragma unroll
            for (int j = 0; j < 4; ++j) {
                alo.h[j] = f2bf2(fmaxf(bf2f(ulo[2*j])   - wf[2*j],     0.f),
                                 fmaxf(bf2f(ulo[2*j+1]) - wf[2*j+1],   0.f));
                ahi.h[j] = f2bf2(fmaxf(bf2f(uhi[2*j])   - wf[8+2*j],   0.f),
                                 fmaxf(bf2f(uhi[2*j+1]) - wf[8+2*j+1], 0.f));
            }

            float4v c2[4];
#pragma unroll
            for (int t = 0; t < 4; ++t) {
                c2[t] = __builtin_amdgcn_mfma_f32_16x16x32_bf16(
                    alo.v, w2f[0][t], (float4v){0.f,0.f,0.f,0.f}, 0, 0, 0);
                c2[t] = __builtin_amdgcn_mfma_f32_16x16x32_bf16(
                    ahi.v, w2f[1][t], c2[t], 0, 0, 0);
            }

#pragma unroll
            for (int r = 0; r < 4; ++r) {
                const int row = q * 4 + r;
#pragma unroll
                for (int t = 0; t < 4; ++t) {
                    const float v = c2[t][r] + b2c[t];
                    if (row < rows) vmax[t] = fmaxf(vmax[t], v);
                }
            }
        }

#pragma unroll
        for (int t = 0; t < 4; ++t) {
            vmax[t] = fmaxf(vmax[t], __shfl_xor(vmax[t], 16));
            vmax[t] = fmaxf(vmax[t], __shfl_xor(vmax[t], 32));
        }
        float v = vmax[0];
        v = (q == 1) ? vmax[1] : v;
        v = (q == 2) ? vmax[2] : v;
        v = (q == 3) ? vmax[3] : v;
        out[node * 64 + lane] = v;
    }
}

extern "C" void kernel_launch(void* const* d_in, const int* in_sizes, int n_in,
                              void* d_out, int out_size, void* d_ws, size_t ws_size,
                              hipStream_t stream) {
    const float* x   = (const float*)d_in[0];
    const float* pos = (const float*)d_in[1];
    const float* W1  = (const float*)d_in[2];
    const float* b1  = (const float*)d_in[3];
    const float* W2  = (const float*)d_in[4];
    const float* b2  = (const float*)d_in[5];
    const int*   ei  = (const int*)d_in[6];

    char* ws = (char*)d_ws;
    int* gcnt      = (int*)(ws + 0);          // 1 KB
    int* bktD      = (int*)(ws + 1024);       // 7,225,344 B
    int* csr       = (int*)(ws + 7226368);    // 7,225,344 B
    int* nodeStart = (int*)(ws + 14451712);   // 400,000 B
    int* nodeDeg   = (int*)(ws + 14851712);   // 400,000 B
    unsigned short* u16 = (unsigned short*)(ws + 15251712);  // 12.8 MB
    unsigned short* w16 = (unsigned short*)(ws + 28051712);  // 12.8 MB

    hipMemsetAsync(gcnt, 0, 1024, stream);
    precompute_kernel<<<512, 256, 0, stream>>>(x, pos, W1, b1, u16, w16);
    partition_kernel<<<(N_EDGES + BATCH - 1) / BATCH, 256, 0, stream>>>(ei, gcnt, bktD);
    csrify_kernel<<<NBKT, 1024, 0, stream>>>(gcnt, bktD, nodeStart, nodeDeg, csr);
    aggregate_kernel<<<(N_NODES + 63) / 64, 256, 0, stream>>>(
        u16, w16, W2, b2, nodeStart, nodeDeg, csr, (float*)d_out);
}